// Round 8
// baseline (412.334 us; speedup 1.0000x reference)
//
#include <hip/hip_runtime.h>
#include <hip/hip_bf16.h>

typedef __attribute__((ext_vector_type(8))) short short8_t;
typedef __attribute__((ext_vector_type(4))) float f32x4;

__device__ __forceinline__ short f2bf(float x){
  union { float f; unsigned u; } v; v.f = x;
  unsigned r = v.u + 0x7fffu + ((v.u >> 16) & 1u);
  return (short)(r >> 16);
}
__device__ __forceinline__ unsigned cvtpk(float lo, float hi){
  unsigned r;
  asm volatile("v_cvt_pk_bf16_f32 %0, %1, %2" : "=v"(r) : "v"(lo), "v"(hi));
  return r;
}
__device__ __forceinline__ float bf2f(unsigned short u){
  union { unsigned u; float f; } v; v.u = ((unsigned)u) << 16; return v.f;
}

// Both W -> bf16 fragment layouts in one launch.
__global__ __launch_bounds__(256) void k_wconv2(const float* __restrict__ W1, short* __restrict__ Wb1,
                                                const float* __restrict__ W2, short* __restrict__ Wb2){
  int tid = blockIdx.x*256 + threadIdx.x;
  const float* W; short* Wb; int t;
  if (tid < 64*2048){ W = W1; Wb = Wb1; t = tid; }
  else if (tid < 64*2048 + 2*2048){ W = W2; Wb = Wb2; t = tid - 64*2048; }
  else return;
  int e  = t & 7;
  int l  = (t >> 3) & 63;
  int nt = (t >> 9) & 3;
  int kt = t >> 11;
  int k  = kt*32 + (l >> 4)*8 + e;
  int col = nt*16 + (l & 15);
  Wb[t] = f2bf(W[(size_t)k*64 + col]);
}

// FUSED-1 v2: odd blocks = hist (+rank), even blocks = GEMM1 with K-split x2.
// GEMM: block = 4 waves = 2 row-tiles x 2 K-halves; 32 rows/block.
// Wave (tile,kh) computes rows [row0,row0+16) over K-half kh; kh=1 publishes acc via LDS; kh=0 reduces+stores fp32.
__global__ __launch_bounds__(256) void k_hist_gemm1(const int* __restrict__ ei, int* __restrict__ cnt,
                                                    int* __restrict__ rank, int E,
                                                    const float* __restrict__ A, const short* __restrict__ Wb,
                                                    float* __restrict__ h1raw, int M, int HB){
  __shared__ unsigned short lds[4*16*256];   // 32 KB: 8 KB per wave
  int b = blockIdx.x;
  int tid = threadIdx.x;
  if (b & 1){
    for (int i = (b>>1)*256 + tid; i < E; i += HB*256)
      rank[i] = atomicAdd(&cnt[ei[E + i]], 1);
    return;
  }
  int g = b >> 1;
  int wid = tid >> 6, lane = tid & 63;
  int tile = wid >> 1, kh = wid & 1;
  int row0 = g*32 + tile*16;
  int rfrag = lane & 15, grp = lane >> 4;
  char* ldsb = (char*)lds;
  const short8_t* wb = (const short8_t*)Wb + lane;
  f32x4 acc0 = {0.f,0.f,0.f,0.f}, acc1 = acc0, acc2 = acc0, acc3 = acc0;

  int wbase = wid*16*512;                  // wave's 8KB LDS region
  int wsel  = (lane >> 1);
  int whalf = (lane & 1) << 3;

  for (int ko = 0; ko < 4; ++ko){
    int kcol = kh*1024 + ko*256;
    #pragma unroll
    for (int r = 0; r < 16; ++r){
      int rowc = row0 + r; if (rowc >= M) rowc = M - 1;
      const float4 a = *(const float4*)(A + (size_t)rowc*2048 + kcol + lane*4);
      uint2 p; p.x = cvtpk(a.x, a.y); p.y = cvtpk(a.z, a.w);
      *(uint2*)(ldsb + wbase + r*512 + ((wsel ^ (r & 7)) << 4) + whalf) = p;
    }
    asm volatile("s_waitcnt lgkmcnt(0)" ::: "memory");
    #pragma unroll
    for (int kt = 0; kt < 8; ++kt){
      short8_t af = *(const short8_t*)(ldsb + wbase + rfrag*512 + ((((kt<<2) + grp) ^ (rfrag & 7)) << 4));
      int ktg = kh*32 + ko*8 + kt;
      short8_t b0 = wb[(ktg*4+0)*64];
      short8_t b1 = wb[(ktg*4+1)*64];
      short8_t b2 = wb[(ktg*4+2)*64];
      short8_t b3 = wb[(ktg*4+3)*64];
      acc0 = __builtin_amdgcn_mfma_f32_16x16x32_bf16(af, b0, acc0, 0,0,0);
      acc1 = __builtin_amdgcn_mfma_f32_16x16x32_bf16(af, b1, acc1, 0,0,0);
      acc2 = __builtin_amdgcn_mfma_f32_16x16x32_bf16(af, b2, acc2, 0,0,0);
      acc3 = __builtin_amdgcn_mfma_f32_16x16x32_bf16(af, b3, acc3, 0,0,0);
    }
  }

  // K-half reduction via LDS (kh=1 publishes into its own stage area, stride 80B for alignment)
  if (kh == 1){
    float* xch = (float*)(ldsb + wbase);
    *(f32x4*)(xch + lane*20 +  0) = acc0;
    *(f32x4*)(xch + lane*20 +  4) = acc1;
    *(f32x4*)(xch + lane*20 +  8) = acc2;
    *(f32x4*)(xch + lane*20 + 12) = acc3;
  }
  __syncthreads();
  if (kh == 1) return;
  {
    float* px = (float*)(ldsb + (wid+1)*16*512);
    acc0 += *(const f32x4*)(px + lane*20 +  0);
    acc1 += *(const f32x4*)(px + lane*20 +  4);
    acc2 += *(const f32x4*)(px + lane*20 +  8);
    acc3 += *(const f32x4*)(px + lane*20 + 12);
  }

  // C/D: col = lane&15, row = (lane>>4)*4 + reg ; unscaled fp32 out
  int orow = row0 + grp*4;
  float* op = h1raw + (size_t)orow*64 + rfrag;
  #pragma unroll
  for (int reg = 0; reg < 4; ++reg){
    if (orow + reg < M){
      op[reg*64 +  0] = acc0[reg];
      op[reg*64 + 16] = acc1[reg];
      op[reg*64 + 32] = acc2[reg];
      op[reg*64 + 48] = acc3[reg];
    }
  }
}

// ---- parallel scan ----
__global__ __launch_bounds__(256) void k_part(const int* __restrict__ cnt, int* __restrict__ partial, int N){
  int b = blockIdx.x, t = threadIdx.x;
  int chunk = (N + 255) >> 8;
  int lo = b*chunk, hi = lo + chunk; if (hi > N) hi = N;
  int s = 0;
  for (int i = lo + t; i < hi; i += 256) s += cnt[i];
  __shared__ int sm[256];
  sm[t] = s; __syncthreads();
  for (int d = 128; d; d >>= 1){ if (t < d) sm[t] += sm[t+d]; __syncthreads(); }
  if (t == 0) partial[b] = sm[0];
}

__global__ __launch_bounds__(256) void k_scan2(const int* __restrict__ cnt, const int* __restrict__ partial,
                                               int* __restrict__ off, float* __restrict__ dinv, int N){
  int b = blockIdx.x, t = threadIdx.x;
  __shared__ int ps[256];
  ps[t] = partial[t]; __syncthreads();
  for (int d = 1; d < 256; d <<= 1){
    int v = (t >= d) ? ps[t-d] : 0; __syncthreads(); ps[t] += v; __syncthreads();
  }
  int base  = b ? ps[b-1] : 0;
  int total = ps[255];
  int chunk = (N + 255) >> 8;
  int lo = b*chunk, hi = lo + chunk; if (hi > N) hi = N;
  __shared__ int vs[256];
  int run = base;
  for (int j0 = lo; j0 < hi; j0 += 256){
    int i = j0 + t;
    int c = (i < hi) ? cnt[i] : 0;
    vs[t] = c; __syncthreads();
    for (int d = 1; d < 256; d <<= 1){
      int v = (t >= d) ? vs[t-d] : 0; __syncthreads(); vs[t] += v; __syncthreads();
    }
    if (i < hi){
      off[i] = run + vs[t] - c;
      dinv[i] = rsqrtf((float)(c + 1));
    }
    run += vs[255];
    __syncthreads();
  }
  if (b == 255 && t == 0) off[N] = total;
}

// FUSED-2: blocks [0,EB) = atomic-free scatter; blocks [EB,EB+SB) = scale h1raw*dinv -> bf16 h1.
__global__ __launch_bounds__(256) void k_scatter_scale(const int* __restrict__ ei, const int* __restrict__ off,
                                                       const int* __restrict__ rank, int* __restrict__ ebuf, int E,
                                                       const float* __restrict__ h1raw, const float* __restrict__ dinv,
                                                       unsigned short* __restrict__ h1, int total8, int EB){
  if ((int)blockIdx.x < EB){
    int i = blockIdx.x*256 + threadIdx.x;
    if (i < E){
      int s = ei[i], d = ei[E + i];
      ebuf[off[d] + rank[i]] = s;
    }
    return;
  }
  int t = (blockIdx.x - EB)*256 + threadIdx.x;
  if (t >= total8) return;
  int base = t*8;
  float dv = dinv[base >> 6];
  const float4 a0 = *(const float4*)(h1raw + base);
  const float4 a1 = *(const float4*)(h1raw + base + 4);
  uint2 p0; p0.x = cvtpk(a0.x*dv, a0.y*dv); p0.y = cvtpk(a0.z*dv, a0.w*dv);
  uint2 p1; p1.x = cvtpk(a1.x*dv, a1.y*dv); p1.y = cvtpk(a1.z*dv, a1.w*dv);
  uint4 o; o.x = p0.x; o.y = p0.y; o.z = p1.x; o.w = p1.y;
  *(uint4*)(h1 + base) = o;
}

// GEMM2 (K=64): bf16 A, dinv-scaled epilogue.
template<int KTILES>
__global__ __launch_bounds__(256) void k_gemm_sm(const unsigned short* __restrict__ Ah,
                                                 const short* __restrict__ Wb, const float* __restrict__ dinv,
                                                 unsigned short* __restrict__ out, int M, int lda){
  int wid = threadIdx.x >> 6, lane = threadIdx.x & 63;
  int row0 = (blockIdx.x*4 + wid)*16;
  if (row0 >= M) return;
  int r = lane & 15, g = lane >> 4;
  const short8_t* wb = (const short8_t*)Wb + lane;
  f32x4 acc0 = {0.f,0.f,0.f,0.f}, acc1 = acc0, acc2 = acc0, acc3 = acc0;
  #pragma unroll
  for (int kt = 0; kt < KTILES; ++kt){
    short8_t af = *(const short8_t*)(Ah + (size_t)(row0 + r)*lda + kt*32 + g*8);
    short8_t b0 = wb[(kt*4+0)*64];
    short8_t b1 = wb[(kt*4+1)*64];
    short8_t b2 = wb[(kt*4+2)*64];
    short8_t b3 = wb[(kt*4+3)*64];
    acc0 = __builtin_amdgcn_mfma_f32_16x16x32_bf16(af, b0, acc0, 0,0,0);
    acc1 = __builtin_amdgcn_mfma_f32_16x16x32_bf16(af, b1, acc1, 0,0,0);
    acc2 = __builtin_amdgcn_mfma_f32_16x16x32_bf16(af, b2, acc2, 0,0,0);
    acc3 = __builtin_amdgcn_mfma_f32_16x16x32_bf16(af, b3, acc3, 0,0,0);
  }
  int orow = row0 + g*4;
  float d0 = dinv[orow], d1 = dinv[orow+1], d2 = dinv[orow+2], d3 = dinv[orow+3];
  unsigned short* op = out + (size_t)orow*64 + r;
  op[0*64 +  0] = (unsigned short)f2bf(acc0[0]*d0);
  op[0*64 + 16] = (unsigned short)f2bf(acc1[0]*d0);
  op[0*64 + 32] = (unsigned short)f2bf(acc2[0]*d0);
  op[0*64 + 48] = (unsigned short)f2bf(acc3[0]*d0);
  op[1*64 +  0] = (unsigned short)f2bf(acc0[1]*d1);
  op[1*64 + 16] = (unsigned short)f2bf(acc1[1]*d1);
  op[1*64 + 32] = (unsigned short)f2bf(acc2[1]*d1);
  op[1*64 + 48] = (unsigned short)f2bf(acc3[1]*d1);
  op[2*64 +  0] = (unsigned short)f2bf(acc0[2]*d2);
  op[2*64 + 16] = (unsigned short)f2bf(acc1[2]*d2);
  op[2*64 + 32] = (unsigned short)f2bf(acc2[2]*d2);
  op[2*64 + 48] = (unsigned short)f2bf(acc3[2]*d2);
  op[3*64 +  0] = (unsigned short)f2bf(acc0[3]*d3);
  op[3*64 + 16] = (unsigned short)f2bf(acc1[3]*d3);
  op[3*64 + 32] = (unsigned short)f2bf(acc2[3]*d3);
  op[3*64 + 48] = (unsigned short)f2bf(acc3[3]*d3);
}

template<bool FUSE>
__global__ __launch_bounds__(256) void k_agg(const unsigned short* __restrict__ hin, const int* __restrict__ off,
                                             const int* __restrict__ ebuf, const float* __restrict__ dinv,
                                             const float* __restrict__ bias, void* __restrict__ outp, int N){
  int lane = threadIdx.x & 63, wid = threadIdx.x >> 6;
  float b = bias[lane];
  float fsum = 0.f;
  int stride = gridDim.x*4;
  for (int i = blockIdx.x*4 + wid; i < N; i += stride){
    float acc = bf2f(hin[(size_t)i*64 + lane]);
    int j  = off[i];
    int j1 = off[i+1];
    for (; j + 4 <= j1; j += 4){
      int s0 = ebuf[j], s1 = ebuf[j+1], s2 = ebuf[j+2], s3 = ebuf[j+3];
      acc += bf2f(hin[(size_t)s0*64 + lane]);
      acc += bf2f(hin[(size_t)s1*64 + lane]);
      acc += bf2f(hin[(size_t)s2*64 + lane]);
      acc += bf2f(hin[(size_t)s3*64 + lane]);
    }
    for (; j < j1; ++j){
      int s = ebuf[j];
      acc += bf2f(hin[(size_t)s*64 + lane]);
    }
    float z = fmaxf(dinv[i]*acc + b, 0.f);
    if (FUSE) fsum += z;
    else ((unsigned short*)outp)[(size_t)i*64 + lane] = (unsigned short)f2bf(z);
  }
  if (FUSE){
    __shared__ float sm[4][64];
    sm[wid][lane] = fsum;
    __syncthreads();
    if (wid == 0)
      ((float*)outp)[(size_t)blockIdx.x*64 + lane] = sm[0][lane] + sm[1][lane] + sm[2][lane] + sm[3][lane];
  }
}

__global__ __launch_bounds__(256) void k_final(const float* __restrict__ part, float* __restrict__ out,
                                               int NB, float invN){
  int f = blockIdx.x;
  float s = 0.f;
  for (int b = threadIdx.x; b < NB; b += 256) s += part[(size_t)b*64 + f];
  __shared__ float sm[256];
  sm[threadIdx.x] = s; __syncthreads();
  for (int d = 128; d > 0; d >>= 1){
    if (threadIdx.x < d) sm[threadIdx.x] += sm[threadIdx.x + d];
    __syncthreads();
  }
  if (threadIdx.x == 0) out[f] = sm[0]*invN;
}

extern "C" void kernel_launch(void* const* d_in, const int* in_sizes, int n_in,
                              void* d_out, int out_size, void* d_ws, size_t ws_size,
                              hipStream_t stream){
  const float* x  = (const float*)d_in[0];
  const int*   ei = (const int*)d_in[1];
  const float* W1 = (const float*)d_in[2];
  const float* b1 = (const float*)d_in[3];
  const float* W2 = (const float*)d_in[4];
  const float* b2 = (const float*)d_in[5];
  float* out = (float*)d_out;

  const int IN = 2048;
  int N = in_sizes[0] / IN;      // 50000
  int E = in_sizes[1] / 2;       // 1.6M

  char* w = (char*)d_ws;
  auto alloc = [&](size_t bytes){ char* p = w; w += (bytes + 255) & ~255ULL; return (void*)p; };
  int*   cnt     = (int*)  alloc((size_t)N*4);
  int*   off     = (int*)  alloc((size_t)(N+1)*4);
  float* dinv    = (float*)alloc((size_t)N*4);
  int*   partial = (int*)  alloc(256*4);
  int*   rank    = (int*)  alloc((size_t)E*4);
  int*   ebuf    = (int*)  alloc((size_t)E*4);
  short* Wb1     = (short*)alloc((size_t)64*2048*2);
  short* Wb2     = (short*)alloc((size_t)2*2048*2);
  float* h1raw   = (float*)alloc((size_t)N*64*4);
  unsigned short* h1 = (unsigned short*)alloc((size_t)N*64*2);
  unsigned short* z1 = (unsigned short*)alloc((size_t)N*64*2);
  const int NB2 = 2048;
  float* part    = (float*)alloc((size_t)NB2*64*4);

  int EB = (E + 255)/256;            // 6250
  int GB = (N + 31)/32;              // 1563  (K-split gemm blocks)
  int HB = GB;                       // matched hist blocks, interleaved 1:1
  int total8 = N*8;
  int SB = (total8 + 255)/256;
  int smblocks = ((N + 15)/16 + 3)/4;

  hipMemsetAsync(cnt, 0, (size_t)N*4, stream);
  k_wconv2 <<<(64*2048 + 2*2048 + 255)/256, 256, 0, stream>>>(W1, Wb1, W2, Wb2);
  k_hist_gemm1<<<2*GB, 256, 0, stream>>>(ei, cnt, rank, E, x, Wb1, h1raw, N, HB);
  k_part   <<<256, 256, 0, stream>>>(cnt, partial, N);
  k_scan2  <<<256, 256, 0, stream>>>(cnt, partial, off, dinv, N);
  k_scatter_scale<<<EB + SB, 256, 0, stream>>>(ei, off, rank, ebuf, E, h1raw, dinv, h1, total8, EB);
  k_agg<false><<<NB2, 256, 0, stream>>>(h1, off, ebuf, dinv, b1, (void*)z1, N);
  k_gemm_sm<2><<<smblocks, 256, 0, stream>>>(z1, Wb2, dinv, h1, N, 64);
  k_agg<true> <<<NB2, 256, 0, stream>>>(h1, off, ebuf, dinv, b2, (void*)part, N);
  k_final  <<<64, 256, 0, stream>>>(part, out, NB2, 1.0f/(float)N);
}

// Round 9
// 397.489 us; speedup vs baseline: 1.0373x; 1.0373x over previous
//
#include <hip/hip_runtime.h>
#include <hip/hip_bf16.h>

typedef __attribute__((ext_vector_type(8))) short short8_t;
typedef __attribute__((ext_vector_type(4))) float f32x4;

__device__ __forceinline__ short f2bf(float x){
  union { float f; unsigned u; } v; v.f = x;
  unsigned r = v.u + 0x7fffu + ((v.u >> 16) & 1u);
  return (short)(r >> 16);
}
__device__ __forceinline__ unsigned pack2(float lo, float hi){
  return (unsigned)(unsigned short)f2bf(lo) | ((unsigned)(unsigned short)f2bf(hi) << 16);
}
__device__ __forceinline__ float bf2f(unsigned short u){
  union { unsigned u; float f; } v; v.u = ((unsigned)u) << 16; return v.f;
}

// Both W -> bf16 fragment layouts in one launch.
__global__ __launch_bounds__(256) void k_wconv2(const float* __restrict__ W1, short* __restrict__ Wb1,
                                                const float* __restrict__ W2, short* __restrict__ Wb2){
  int tid = blockIdx.x*256 + threadIdx.x;
  const float* W; short* Wb; int t;
  if (tid < 64*2048){ W = W1; Wb = Wb1; t = tid; }
  else if (tid < 64*2048 + 2*2048){ W = W2; Wb = Wb2; t = tid - 64*2048; }
  else return;
  int e  = t & 7;
  int l  = (t >> 3) & 63;
  int nt = (t >> 9) & 3;
  int kt = t >> 11;
  int k  = kt*32 + (l >> 4)*8 + e;
  int col = nt*16 + (l & 15);
  Wb[t] = f2bf(W[(size_t)k*64 + col]);
}

// FUSED-1: odd blocks = hist (+rank), even blocks = GEMM1 with K-split x2.
// GEMM block = 4 waves = 2 row-tiles x 2 K-halves; 32 rows/block.
__global__ __launch_bounds__(256) void k_hist_gemm1(const int* __restrict__ ei, int* __restrict__ cnt,
                                                    int* __restrict__ rank, int E,
                                                    const float* __restrict__ A, const short* __restrict__ Wb,
                                                    float* __restrict__ h1raw, int M, int HB){
  __shared__ unsigned short lds[4*16*256];   // 32 KB: 8 KB per wave
  int b = blockIdx.x;
  int tid = threadIdx.x;
  if (b & 1){
    for (int i = (b>>1)*256 + tid; i < E; i += HB*256)
      rank[i] = atomicAdd(&cnt[ei[E + i]], 1);
    return;
  }
  int g = b >> 1;
  int wid = tid >> 6, lane = tid & 63;
  int tile = wid >> 1, kh = wid & 1;
  int row0 = g*32 + tile*16;
  int rfrag = lane & 15, grp = lane >> 4;
  char* ldsb = (char*)lds;
  const short8_t* wb = (const short8_t*)Wb + lane;
  f32x4 acc0 = {0.f,0.f,0.f,0.f}, acc1 = acc0, acc2 = acc0, acc3 = acc0;

  int wbase = wid*16*512;                  // wave's 8KB LDS region
  int wsel  = (lane >> 1);
  int whalf = (lane & 1) << 3;

  for (int ko = 0; ko < 4; ++ko){
    int kcol = kh*1024 + ko*256;
    #pragma unroll
    for (int r = 0; r < 16; ++r){
      int rowc = row0 + r; if (rowc >= M) rowc = M - 1;
      const float4 a = *(const float4*)(A + (size_t)rowc*2048 + kcol + lane*4);
      uint2 p; p.x = pack2(a.x, a.y); p.y = pack2(a.z, a.w);
      *(uint2*)(ldsb + wbase + r*512 + ((wsel ^ (r & 7)) << 4) + whalf) = p;
    }
    asm volatile("s_waitcnt lgkmcnt(0)" ::: "memory");
    #pragma unroll
    for (int kt = 0; kt < 8; ++kt){
      short8_t af = *(const short8_t*)(ldsb + wbase + rfrag*512 + ((((kt<<2) + grp) ^ (rfrag & 7)) << 4));
      int ktg = kh*32 + ko*8 + kt;
      short8_t b0 = wb[(ktg*4+0)*64];
      short8_t b1 = wb[(ktg*4+1)*64];
      short8_t b2 = wb[(ktg*4+2)*64];
      short8_t b3 = wb[(ktg*4+3)*64];
      acc0 = __builtin_amdgcn_mfma_f32_16x16x32_bf16(af, b0, acc0, 0,0,0);
      acc1 = __builtin_amdgcn_mfma_f32_16x16x32_bf16(af, b1, acc1, 0,0,0);
      acc2 = __builtin_amdgcn_mfma_f32_16x16x32_bf16(af, b2, acc2, 0,0,0);
      acc3 = __builtin_amdgcn_mfma_f32_16x16x32_bf16(af, b3, acc3, 0,0,0);
    }
  }

  // K-half reduction via LDS (kh=1 publishes, kh=0 reduces+stores fp32)
  if (kh == 1){
    float* xch = (float*)(ldsb + wbase);
    *(f32x4*)(xch + lane*20 +  0) = acc0;
    *(f32x4*)(xch + lane*20 +  4) = acc1;
    *(f32x4*)(xch + lane*20 +  8) = acc2;
    *(f32x4*)(xch + lane*20 + 12) = acc3;
  }
  __syncthreads();
  if (kh == 1) return;
  {
    float* px = (float*)(ldsb + (wid+1)*16*512);
    acc0 += *(const f32x4*)(px + lane*20 +  0);
    acc1 += *(const f32x4*)(px + lane*20 +  4);
    acc2 += *(const f32x4*)(px + lane*20 +  8);
    acc3 += *(const f32x4*)(px + lane*20 + 12);
  }

  int orow = row0 + grp*4;
  float* op = h1raw + (size_t)orow*64 + rfrag;
  #pragma unroll
  for (int reg = 0; reg < 4; ++reg){
    if (orow + reg < M){
      op[reg*64 +  0] = acc0[reg];
      op[reg*64 + 16] = acc1[reg];
      op[reg*64 + 32] = acc2[reg];
      op[reg*64 + 48] = acc3[reg];
    }
  }
}

// ---- parallel scan ----
__global__ __launch_bounds__(256) void k_part(const int* __restrict__ cnt, int* __restrict__ partial, int N){
  int b = blockIdx.x, t = threadIdx.x;
  int chunk = (N + 255) >> 8;
  int lo = b*chunk, hi = lo + chunk; if (hi > N) hi = N;
  int s = 0;
  for (int i = lo + t; i < hi; i += 256) s += cnt[i];
  __shared__ int sm[256];
  sm[t] = s; __syncthreads();
  for (int d = 128; d; d >>= 1){ if (t < d) sm[t] += sm[t+d]; __syncthreads(); }
  if (t == 0) partial[b] = sm[0];
}

__global__ __launch_bounds__(256) void k_scan2(const int* __restrict__ cnt, const int* __restrict__ partial,
                                               int* __restrict__ off, float* __restrict__ dinv, int N){
  int b = blockIdx.x, t = threadIdx.x;
  __shared__ int ps[256];
  ps[t] = partial[t]; __syncthreads();
  for (int d = 1; d < 256; d <<= 1){
    int v = (t >= d) ? ps[t-d] : 0; __syncthreads(); ps[t] += v; __syncthreads();
  }
  int base  = b ? ps[b-1] : 0;
  int total = ps[255];
  int chunk = (N + 255) >> 8;
  int lo = b*chunk, hi = lo + chunk; if (hi > N) hi = N;
  __shared__ int vs[256];
  int run = base;
  for (int j0 = lo; j0 < hi; j0 += 256){
    int i = j0 + t;
    int c = (i < hi) ? cnt[i] : 0;
    vs[t] = c; __syncthreads();
    for (int d = 1; d < 256; d <<= 1){
      int v = (t >= d) ? vs[t-d] : 0; __syncthreads(); vs[t] += v; __syncthreads();
    }
    if (i < hi){
      off[i] = run + vs[t] - c;
      dinv[i] = rsqrtf((float)(c + 1));
    }
    run += vs[255];
    __syncthreads();
  }
  if (b == 255 && t == 0) off[N] = total;
}

// FUSED-2: blocks [0,EB) = atomic-free scatter; blocks [EB,EB+SB) = scale h1raw*dinv -> bf16 h1.
__global__ __launch_bounds__(256) void k_scatter_scale(const int* __restrict__ ei, const int* __restrict__ off,
                                                       const int* __restrict__ rank, int* __restrict__ ebuf, int E,
                                                       const float* __restrict__ h1raw, const float* __restrict__ dinv,
                                                       unsigned short* __restrict__ h1, int total8, int EB){
  if ((int)blockIdx.x < EB){
    int i = blockIdx.x*256 + threadIdx.x;
    if (i < E){
      int s = ei[i], d = ei[E + i];
      ebuf[off[d] + rank[i]] = s;
    }
    return;
  }
  int t = (blockIdx.x - EB)*256 + threadIdx.x;
  if (t >= total8) return;
  int base = t*8;
  float dv = dinv[base >> 6];
  const float4 a0 = *(const float4*)(h1raw + base);
  const float4 a1 = *(const float4*)(h1raw + base + 4);
  short8_t o;
  o[0]=f2bf(a0.x*dv); o[1]=f2bf(a0.y*dv); o[2]=f2bf(a0.z*dv); o[3]=f2bf(a0.w*dv);
  o[4]=f2bf(a1.x*dv); o[5]=f2bf(a1.y*dv); o[6]=f2bf(a1.z*dv); o[7]=f2bf(a1.w*dv);
  *(short8_t*)(h1 + base) = o;
}

// GEMM2 (K=64): bf16 A, dinv-scaled epilogue.
template<int KTILES>
__global__ __launch_bounds__(256) void k_gemm_sm(const unsigned short* __restrict__ Ah,
                                                 const short* __restrict__ Wb, const float* __restrict__ dinv,
                                                 unsigned short* __restrict__ out, int M, int lda){
  int wid = threadIdx.x >> 6, lane = threadIdx.x & 63;
  int row0 = (blockIdx.x*4 + wid)*16;
  if (row0 >= M) return;
  int r = lane & 15, g = lane >> 4;
  const short8_t* wb = (const short8_t*)Wb + lane;
  f32x4 acc0 = {0.f,0.f,0.f,0.f}, acc1 = acc0, acc2 = acc0, acc3 = acc0;
  #pragma unroll
  for (int kt = 0; kt < KTILES; ++kt){
    short8_t af = *(const short8_t*)(Ah + (size_t)(row0 + r)*lda + kt*32 + g*8);
    short8_t b0 = wb[(kt*4+0)*64];
    short8_t b1 = wb[(kt*4+1)*64];
    short8_t b2 = wb[(kt*4+2)*64];
    short8_t b3 = wb[(kt*4+3)*64];
    acc0 = __builtin_amdgcn_mfma_f32_16x16x32_bf16(af, b0, acc0, 0,0,0);
    acc1 = __builtin_amdgcn_mfma_f32_16x16x32_bf16(af, b1, acc1, 0,0,0);
    acc2 = __builtin_amdgcn_mfma_f32_16x16x32_bf16(af, b2, acc2, 0,0,0);
    acc3 = __builtin_amdgcn_mfma_f32_16x16x32_bf16(af, b3, acc3, 0,0,0);
  }
  int orow = row0 + g*4;
  float d0 = dinv[orow], d1 = dinv[orow+1], d2 = dinv[orow+2], d3 = dinv[orow+3];
  unsigned short* op = out + (size_t)orow*64 + r;
  op[0*64 +  0] = (unsigned short)f2bf(acc0[0]*d0);
  op[0*64 + 16] = (unsigned short)f2bf(acc1[0]*d0);
  op[0*64 + 32] = (unsigned short)f2bf(acc2[0]*d0);
  op[0*64 + 48] = (unsigned short)f2bf(acc3[0]*d0);
  op[1*64 +  0] = (unsigned short)f2bf(acc0[1]*d1);
  op[1*64 + 16] = (unsigned short)f2bf(acc1[1]*d1);
  op[1*64 + 32] = (unsigned short)f2bf(acc2[1]*d1);
  op[1*64 + 48] = (unsigned short)f2bf(acc3[1]*d1);
  op[2*64 +  0] = (unsigned short)f2bf(acc0[2]*d2);
  op[2*64 + 16] = (unsigned short)f2bf(acc1[2]*d2);
  op[2*64 + 32] = (unsigned short)f2bf(acc2[2]*d2);
  op[2*64 + 48] = (unsigned short)f2bf(acc3[2]*d2);
  op[3*64 +  0] = (unsigned short)f2bf(acc0[3]*d3);
  op[3*64 + 16] = (unsigned short)f2bf(acc1[3]*d3);
  op[3*64 + 32] = (unsigned short)f2bf(acc2[3]*d3);
  op[3*64 + 48] = (unsigned short)f2bf(acc3[3]*d3);
}

template<bool FUSE>
__global__ __launch_bounds__(256) void k_agg(const unsigned short* __restrict__ hin, const int* __restrict__ off,
                                             const int* __restrict__ ebuf, const float* __restrict__ dinv,
                                             const float* __restrict__ bias, void* __restrict__ outp, int N){
  int lane = threadIdx.x & 63, wid = threadIdx.x >> 6;
  float b = bias[lane];
  float fsum = 0.f;
  int stride = gridDim.x*4;
  for (int i = blockIdx.x*4 + wid; i < N; i += stride){
    float acc = bf2f(hin[(size_t)i*64 + lane]);
    int j  = off[i];
    int j1 = off[i+1];
    for (; j + 4 <= j1; j += 4){
      int s0 = ebuf[j], s1 = ebuf[j+1], s2 = ebuf[j+2], s3 = ebuf[j+3];
      acc += bf2f(hin[(size_t)s0*64 + lane]);
      acc += bf2f(hin[(size_t)s1*64 + lane]);
      acc += bf2f(hin[(size_t)s2*64 + lane]);
      acc += bf2f(hin[(size_t)s3*64 + lane]);
    }
    for (; j < j1; ++j){
      int s = ebuf[j];
      acc += bf2f(hin[(size_t)s*64 + lane]);
    }
    float z = fmaxf(dinv[i]*acc + b, 0.f);
    if (FUSE) fsum += z;
    else ((unsigned short*)outp)[(size_t)i*64 + lane] = (unsigned short)f2bf(z);
  }
  if (FUSE){
    __shared__ float sm[4][64];
    sm[wid][lane] = fsum;
    __syncthreads();
    if (wid == 0)
      ((float*)outp)[(size_t)blockIdx.x*64 + lane] = sm[0][lane] + sm[1][lane] + sm[2][lane] + sm[3][lane];
  }
}

__global__ __launch_bounds__(256) void k_final(const float* __restrict__ part, float* __restrict__ out,
                                               int NB, float invN){
  int f = blockIdx.x;
  float s = 0.f;
  for (int b = threadIdx.x; b < NB; b += 256) s += part[(size_t)b*64 + f];
  __shared__ float sm[256];
  sm[threadIdx.x] = s; __syncthreads();
  for (int d = 128; d > 0; d >>= 1){
    if (threadIdx.x < d) sm[threadIdx.x] += sm[threadIdx.x + d];
    __syncthreads();
  }
  if (threadIdx.x == 0) out[f] = sm[0]*invN;
}

extern "C" void kernel_launch(void* const* d_in, const int* in_sizes, int n_in,
                              void* d_out, int out_size, void* d_ws, size_t ws_size,
                              hipStream_t stream){
  const float* x  = (const float*)d_in[0];
  const int*   ei = (const int*)d_in[1];
  const float* W1 = (const float*)d_in[2];
  const float* b1 = (const float*)d_in[3];
  const float* W2 = (const float*)d_in[4];
  const float* b2 = (const float*)d_in[5];
  float* out = (float*)d_out;

  const int IN = 2048;
  int N = in_sizes[0] / IN;      // 50000
  int E = in_sizes[1] / 2;       // 1.6M

  char* w = (char*)d_ws;
  auto alloc = [&](size_t bytes){ char* p = w; w += (bytes + 255) & ~255ULL; return (void*)p; };
  int*   cnt     = (int*)  alloc((size_t)N*4);
  int*   off     = (int*)  alloc((size_t)(N+1)*4);
  float* dinv    = (float*)alloc((size_t)N*4);
  int*   partial = (int*)  alloc(256*4);
  int*   rank    = (int*)  alloc((size_t)E*4);
  int*   ebuf    = (int*)  alloc((size_t)E*4);
  short* Wb1     = (short*)alloc((size_t)64*2048*2);
  short* Wb2     = (short*)alloc((size_t)2*2048*2);
  float* h1raw   = (float*)alloc((size_t)N*64*4);
  unsigned short* h1 = (unsigned short*)alloc((size_t)N*64*2);
  unsigned short* z1 = (unsigned short*)alloc((size_t)N*64*2);
  const int NB2 = 2048;
  float* part    = (float*)alloc((size_t)NB2*64*4);

  int EB = (E + 255)/256;            // 6250
  int GB = (N + 31)/32;              // 1563  (K-split gemm blocks)
  int HB = GB;                       // matched hist blocks, interleaved 1:1
  int total8 = N*8;
  int SB = (total8 + 255)/256;
  int smblocks = ((N + 15)/16 + 3)/4;

  hipMemsetAsync(cnt, 0, (size_t)N*4, stream);
  k_wconv2 <<<(64*2048 + 2*2048 + 255)/256, 256, 0, stream>>>(W1, Wb1, W2, Wb2);
  k_hist_gemm1<<<2*GB, 256, 0, stream>>>(ei, cnt, rank, E, x, Wb1, h1raw, N, HB);
  k_part   <<<256, 256, 0, stream>>>(cnt, partial, N);
  k_scan2  <<<256, 256, 0, stream>>>(cnt, partial, off, dinv, N);
  k_scatter_scale<<<EB + SB, 256, 0, stream>>>(ei, off, rank, ebuf, E, h1raw, dinv, h1, total8, EB);
  k_agg<false><<<NB2, 256, 0, stream>>>(h1, off, ebuf, dinv, b1, (void*)z1, N);
  k_gemm_sm<2><<<smblocks, 256, 0, stream>>>(z1, Wb2, dinv, h1, N, 64);
  k_agg<true> <<<NB2, 256, 0, stream>>>(h1, off, ebuf, dinv, b2, (void*)part, N);
  k_final  <<<64, 256, 0, stream>>>(part, out, NB2, 1.0f/(float)N);
}

// Round 10
// 363.267 us; speedup vs baseline: 1.1351x; 1.0942x over previous
//
#include <hip/hip_runtime.h>
#include <hip/hip_bf16.h>

typedef __attribute__((ext_vector_type(8))) short short8_t;
typedef __attribute__((ext_vector_type(4))) float f32x4;

__device__ __forceinline__ short f2bf(float x){
  union { float f; unsigned u; } v; v.f = x;
  unsigned r = v.u + 0x7fffu + ((v.u >> 16) & 1u);
  return (short)(r >> 16);
}
__device__ __forceinline__ unsigned pack2(float lo, float hi){
  return (unsigned)(unsigned short)f2bf(lo) | ((unsigned)(unsigned short)f2bf(hi) << 16);
}
__device__ __forceinline__ float bf2f(unsigned short u){
  union { unsigned u; float f; } v; v.u = ((unsigned)u) << 16; return v.f;
}

// Both W -> bf16 fragment layouts in one launch.
__global__ __launch_bounds__(256) void k_wconv2(const float* __restrict__ W1, short* __restrict__ Wb1,
                                                const float* __restrict__ W2, short* __restrict__ Wb2){
  int tid = blockIdx.x*256 + threadIdx.x;
  const float* W; short* Wb; int t;
  if (tid < 64*2048){ W = W1; Wb = Wb1; t = tid; }
  else if (tid < 64*2048 + 2*2048){ W = W2; Wb = Wb2; t = tid - 64*2048; }
  else return;
  int e  = t & 7;
  int l  = (t >> 3) & 63;
  int nt = (t >> 9) & 3;
  int kt = t >> 11;
  int k  = kt*32 + (l >> 4)*8 + e;
  int col = nt*16 + (l & 15);
  Wb[t] = f2bf(W[(size_t)k*64 + col]);
}

// GEMM1 (K-split x2, 32 rows/block) writing UNSCALED bf16 h1, with histogram in the block tail.
// Waves: (tile,kh). kh=1 publishes acc via LDS; kh=0 reduces + stores. Then ALL threads hist a slice.
__global__ __launch_bounds__(256) void k_gemm1_hist(const float* __restrict__ A, const short* __restrict__ Wb,
                                                    unsigned short* __restrict__ h1, int M,
                                                    const int* __restrict__ ei, int* __restrict__ cnt,
                                                    int* __restrict__ rank, int E, int GB){
  __shared__ unsigned short lds[4*16*256];   // 32 KB: 8 KB per wave
  int b = blockIdx.x;
  int tid = threadIdx.x;
  int wid = tid >> 6, lane = tid & 63;
  int tile = wid >> 1, kh = wid & 1;
  int row0 = b*32 + tile*16;
  int rfrag = lane & 15, grp = lane >> 4;
  char* ldsb = (char*)lds;
  const short8_t* wb = (const short8_t*)Wb + lane;
  f32x4 acc0 = {0.f,0.f,0.f,0.f}, acc1 = acc0, acc2 = acc0, acc3 = acc0;

  int wbase = wid*16*512;                  // wave's 8KB LDS region
  int wsel  = (lane >> 1);
  int whalf = (lane & 1) << 3;

  for (int ko = 0; ko < 4; ++ko){
    int kcol = kh*1024 + ko*256;
    #pragma unroll
    for (int r = 0; r < 16; ++r){
      int rowc = row0 + r; if (rowc >= M) rowc = M - 1;
      const float4 a = *(const float4*)(A + (size_t)rowc*2048 + kcol + lane*4);
      uint2 p; p.x = pack2(a.x, a.y); p.y = pack2(a.z, a.w);
      *(uint2*)(ldsb + wbase + r*512 + ((wsel ^ (r & 7)) << 4) + whalf) = p;
    }
    asm volatile("s_waitcnt lgkmcnt(0)" ::: "memory");
    #pragma unroll
    for (int kt = 0; kt < 8; ++kt){
      short8_t af = *(const short8_t*)(ldsb + wbase + rfrag*512 + ((((kt<<2) + grp) ^ (rfrag & 7)) << 4));
      int ktg = kh*32 + ko*8 + kt;
      short8_t b0 = wb[(ktg*4+0)*64];
      short8_t b1 = wb[(ktg*4+1)*64];
      short8_t b2 = wb[(ktg*4+2)*64];
      short8_t b3 = wb[(ktg*4+3)*64];
      acc0 = __builtin_amdgcn_mfma_f32_16x16x32_bf16(af, b0, acc0, 0,0,0);
      acc1 = __builtin_amdgcn_mfma_f32_16x16x32_bf16(af, b1, acc1, 0,0,0);
      acc2 = __builtin_amdgcn_mfma_f32_16x16x32_bf16(af, b2, acc2, 0,0,0);
      acc3 = __builtin_amdgcn_mfma_f32_16x16x32_bf16(af, b3, acc3, 0,0,0);
    }
  }

  // K-half reduction via LDS (kh=1 publishes, kh=0 reduces + stores bf16 unscaled)
  if (kh == 1){
    float* xch = (float*)(ldsb + wbase);
    *(f32x4*)(xch + lane*20 +  0) = acc0;
    *(f32x4*)(xch + lane*20 +  4) = acc1;
    *(f32x4*)(xch + lane*20 +  8) = acc2;
    *(f32x4*)(xch + lane*20 + 12) = acc3;
  }
  __syncthreads();
  if (kh == 0){
    float* px = (float*)(ldsb + (wid+1)*16*512);
    acc0 += *(const f32x4*)(px + lane*20 +  0);
    acc1 += *(const f32x4*)(px + lane*20 +  4);
    acc2 += *(const f32x4*)(px + lane*20 +  8);
    acc3 += *(const f32x4*)(px + lane*20 + 12);

    int orow = row0 + grp*4;
    unsigned short* op = h1 + (size_t)orow*64 + rfrag;
    #pragma unroll
    for (int reg = 0; reg < 4; ++reg){
      if (orow + reg < M){
        op[reg*64 +  0] = (unsigned short)f2bf(acc0[reg]);
        op[reg*64 + 16] = (unsigned short)f2bf(acc1[reg]);
        op[reg*64 + 32] = (unsigned short)f2bf(acc2[reg]);
        op[reg*64 + 48] = (unsigned short)f2bf(acc3[reg]);
      }
    }
  }

  // ---- tail: histogram slice for this block (overlaps other blocks' gemm) ----
  int per = (E + GB - 1)/GB;
  int lo = b*per, hi = lo + per; if (hi > E) hi = E;
  for (int i = lo + tid; i < hi; i += 256)
    rank[i] = atomicAdd(&cnt[ei[E + i]], 1);
}

// ---- parallel scan ----
__global__ __launch_bounds__(256) void k_part(const int* __restrict__ cnt, int* __restrict__ partial, int N){
  int b = blockIdx.x, t = threadIdx.x;
  int chunk = (N + 255) >> 8;
  int lo = b*chunk, hi = lo + chunk; if (hi > N) hi = N;
  int s = 0;
  for (int i = lo + t; i < hi; i += 256) s += cnt[i];
  __shared__ int sm[256];
  sm[t] = s; __syncthreads();
  for (int d = 128; d; d >>= 1){ if (t < d) sm[t] += sm[t+d]; __syncthreads(); }
  if (t == 0) partial[b] = sm[0];
}

__global__ __launch_bounds__(256) void k_scan2(const int* __restrict__ cnt, const int* __restrict__ partial,
                                               int* __restrict__ off, float* __restrict__ dinv, int N){
  int b = blockIdx.x, t = threadIdx.x;
  __shared__ int ps[256];
  ps[t] = partial[t]; __syncthreads();
  for (int d = 1; d < 256; d <<= 1){
    int v = (t >= d) ? ps[t-d] : 0; __syncthreads(); ps[t] += v; __syncthreads();
  }
  int base  = b ? ps[b-1] : 0;
  int total = ps[255];
  int chunk = (N + 255) >> 8;
  int lo = b*chunk, hi = lo + chunk; if (hi > N) hi = N;
  __shared__ int vs[256];
  int run = base;
  for (int j0 = lo; j0 < hi; j0 += 256){
    int i = j0 + t;
    int c = (i < hi) ? cnt[i] : 0;
    vs[t] = c; __syncthreads();
    for (int d = 1; d < 256; d <<= 1){
      int v = (t >= d) ? vs[t-d] : 0; __syncthreads(); vs[t] += v; __syncthreads();
    }
    if (i < hi){
      off[i] = run + vs[t] - c;
      dinv[i] = rsqrtf((float)(c + 1));
    }
    run += vs[255];
    __syncthreads();
  }
  if (b == 255 && t == 0) off[N] = total;
}

// Pure atomic-free scatter.
__global__ __launch_bounds__(256) void k_scatter(const int* __restrict__ ei, const int* __restrict__ off,
                                                 const int* __restrict__ rank, int* __restrict__ ebuf, int E){
  int i = blockIdx.x*256 + threadIdx.x;
  if (i < E){
    int s = ei[i], d = ei[E + i];
    ebuf[off[d] + rank[i]] = s;
  }
}

// GEMM2 (K=64): bf16 A, UNSCALED bf16 out.
template<int KTILES>
__global__ __launch_bounds__(256) void k_gemm_sm(const unsigned short* __restrict__ Ah,
                                                 const short* __restrict__ Wb,
                                                 unsigned short* __restrict__ out, int M, int lda){
  int wid = threadIdx.x >> 6, lane = threadIdx.x & 63;
  int row0 = (blockIdx.x*4 + wid)*16;
  if (row0 >= M) return;
  int r = lane & 15, g = lane >> 4;
  const short8_t* wb = (const short8_t*)Wb + lane;
  f32x4 acc0 = {0.f,0.f,0.f,0.f}, acc1 = acc0, acc2 = acc0, acc3 = acc0;
  #pragma unroll
  for (int kt = 0; kt < KTILES; ++kt){
    short8_t af = *(const short8_t*)(Ah + (size_t)(row0 + r)*lda + kt*32 + g*8);
    short8_t b0 = wb[(kt*4+0)*64];
    short8_t b1 = wb[(kt*4+1)*64];
    short8_t b2 = wb[(kt*4+2)*64];
    short8_t b3 = wb[(kt*4+3)*64];
    acc0 = __builtin_amdgcn_mfma_f32_16x16x32_bf16(af, b0, acc0, 0,0,0);
    acc1 = __builtin_amdgcn_mfma_f32_16x16x32_bf16(af, b1, acc1, 0,0,0);
    acc2 = __builtin_amdgcn_mfma_f32_16x16x32_bf16(af, b2, acc2, 0,0,0);
    acc3 = __builtin_amdgcn_mfma_f32_16x16x32_bf16(af, b3, acc3, 0,0,0);
  }
  int orow = row0 + g*4;
  unsigned short* op = out + (size_t)orow*64 + r;
  #pragma unroll
  for (int reg = 0; reg < 4; ++reg){
    op[reg*64 +  0] = (unsigned short)f2bf(acc0[reg]);
    op[reg*64 + 16] = (unsigned short)f2bf(acc1[reg]);
    op[reg*64 + 32] = (unsigned short)f2bf(acc2[reg]);
    op[reg*64 + 48] = (unsigned short)f2bf(acc3[reg]);
  }
}

// Gather-aggregate on UNSCALED h: acc = dinv[i]*h[i] + sum dinv[s]*h[s]; z = relu(dinv[i]*acc + b).
template<bool FUSE>
__global__ __launch_bounds__(256) void k_agg(const unsigned short* __restrict__ hin, const int* __restrict__ off,
                                             const int* __restrict__ ebuf, const float* __restrict__ dinv,
                                             const float* __restrict__ bias, void* __restrict__ outp, int N){
  int lane = threadIdx.x & 63, wid = threadIdx.x >> 6;
  float b = bias[lane];
  float fsum = 0.f;
  int stride = gridDim.x*4;
  for (int i = blockIdx.x*4 + wid; i < N; i += stride){
    float di = dinv[i];
    float acc = di*bf2f(hin[(size_t)i*64 + lane]);
    int j  = off[i];
    int j1 = off[i+1];
    for (; j + 4 <= j1; j += 4){
      int s0 = ebuf[j], s1 = ebuf[j+1], s2 = ebuf[j+2], s3 = ebuf[j+3];
      float w0 = dinv[s0], w1 = dinv[s1], w2 = dinv[s2], w3 = dinv[s3];
      acc += w0*bf2f(hin[(size_t)s0*64 + lane]);
      acc += w1*bf2f(hin[(size_t)s1*64 + lane]);
      acc += w2*bf2f(hin[(size_t)s2*64 + lane]);
      acc += w3*bf2f(hin[(size_t)s3*64 + lane]);
    }
    for (; j < j1; ++j){
      int s = ebuf[j];
      acc += dinv[s]*bf2f(hin[(size_t)s*64 + lane]);
    }
    float z = fmaxf(di*acc + b, 0.f);
    if (FUSE) fsum += z;
    else ((unsigned short*)outp)[(size_t)i*64 + lane] = (unsigned short)f2bf(z);
  }
  if (FUSE){
    __shared__ float sm[4][64];
    sm[wid][lane] = fsum;
    __syncthreads();
    if (wid == 0)
      ((float*)outp)[(size_t)blockIdx.x*64 + lane] = sm[0][lane] + sm[1][lane] + sm[2][lane] + sm[3][lane];
  }
}

__global__ __launch_bounds__(256) void k_final(const float* __restrict__ part, float* __restrict__ out,
                                               int NB, float invN){
  int f = blockIdx.x;
  float s = 0.f;
  for (int b = threadIdx.x; b < NB; b += 256) s += part[(size_t)b*64 + f];
  __shared__ float sm[256];
  sm[threadIdx.x] = s; __syncthreads();
  for (int d = 128; d > 0; d >>= 1){
    if (threadIdx.x < d) sm[threadIdx.x] += sm[threadIdx.x + d];
    __syncthreads();
  }
  if (threadIdx.x == 0) out[f] = sm[0]*invN;
}

extern "C" void kernel_launch(void* const* d_in, const int* in_sizes, int n_in,
                              void* d_out, int out_size, void* d_ws, size_t ws_size,
                              hipStream_t stream){
  const float* x  = (const float*)d_in[0];
  const int*   ei = (const int*)d_in[1];
  const float* W1 = (const float*)d_in[2];
  const float* b1 = (const float*)d_in[3];
  const float* W2 = (const float*)d_in[4];
  const float* b2 = (const float*)d_in[5];
  float* out = (float*)d_out;

  const int IN = 2048;
  int N = in_sizes[0] / IN;      // 50000
  int E = in_sizes[1] / 2;       // 1.6M

  char* w = (char*)d_ws;
  auto alloc = [&](size_t bytes){ char* p = w; w += (bytes + 255) & ~255ULL; return (void*)p; };
  int*   cnt     = (int*)  alloc((size_t)N*4);
  int*   off     = (int*)  alloc((size_t)(N+1)*4);
  float* dinv    = (float*)alloc((size_t)N*4);
  int*   partial = (int*)  alloc(256*4);
  int*   rank    = (int*)  alloc((size_t)E*4);
  int*   ebuf    = (int*)  alloc((size_t)E*4);
  short* Wb1     = (short*)alloc((size_t)64*2048*2);
  short* Wb2     = (short*)alloc((size_t)2*2048*2);
  unsigned short* h1 = (unsigned short*)alloc((size_t)N*64*2);
  unsigned short* z1 = (unsigned short*)alloc((size_t)N*64*2);
  const int NB2 = 2048;
  float* part    = (float*)alloc((size_t)NB2*64*4);

  int EB = (E + 255)/256;            // 6250
  int GB = (N + 31)/32;              // 1563
  int smblocks = ((N + 15)/16 + 3)/4;

  hipMemsetAsync(cnt, 0, (size_t)N*4, stream);
  k_wconv2 <<<(64*2048 + 2*2048 + 255)/256, 256, 0, stream>>>(W1, Wb1, W2, Wb2);
  k_gemm1_hist<<<GB, 256, 0, stream>>>(x, Wb1, h1, N, ei, cnt, rank, E, GB);
  k_part   <<<256, 256, 0, stream>>>(cnt, partial, N);
  k_scan2  <<<256, 256, 0, stream>>>(cnt, partial, off, dinv, N);
  k_scatter<<<EB, 256, 0, stream>>>(ei, off, rank, ebuf, E);
  k_agg<false><<<NB2, 256, 0, stream>>>(h1, off, ebuf, dinv, b1, (void*)z1, N);
  k_gemm_sm<2><<<smblocks, 256, 0, stream>>>(z1, Wb2, h1, N, 64);
  k_agg<true> <<<NB2, 256, 0, stream>>>(h1, off, ebuf, dinv, b2, (void*)part, N);
  k_final  <<<64, 256, 0, stream>>>(part, out, NB2, 1.0f/(float)N);
}

// Round 11
// 347.654 us; speedup vs baseline: 1.1860x; 1.0449x over previous
//
#include <hip/hip_runtime.h>
#include <hip/hip_bf16.h>

typedef __attribute__((ext_vector_type(8))) short short8_t;
typedef __attribute__((ext_vector_type(4))) float f32x4;

__device__ __forceinline__ short f2bf(float x){
  union { float f; unsigned u; } v; v.f = x;
  unsigned r = v.u + 0x7fffu + ((v.u >> 16) & 1u);
  return (short)(r >> 16);
}
__device__ __forceinline__ unsigned pack2(float lo, float hi){
  return (unsigned)(unsigned short)f2bf(lo) | ((unsigned)(unsigned short)f2bf(hi) << 16);
}
__device__ __forceinline__ float bf2f(unsigned short u){
  union { unsigned u; float f; } v; v.u = ((unsigned)u) << 16; return v.f;
}

// Both W -> bf16 fragment layouts in one launch.
__global__ __launch_bounds__(256) void k_wconv2(const float* __restrict__ W1, short* __restrict__ Wb1,
                                                const float* __restrict__ W2, short* __restrict__ Wb2){
  int tid = blockIdx.x*256 + threadIdx.x;
  const float* W; short* Wb; int t;
  if (tid < 64*2048){ W = W1; Wb = Wb1; t = tid; }
  else if (tid < 64*2048 + 2*2048){ W = W2; Wb = Wb2; t = tid - 64*2048; }
  else return;
  int e  = t & 7;
  int l  = (t >> 3) & 63;
  int nt = (t >> 9) & 3;
  int kt = t >> 11;
  int k  = kt*32 + (l >> 4)*8 + e;
  int col = nt*16 + (l & 15);
  Wb[t] = f2bf(W[(size_t)k*64 + col]);
}

// GEMM1 (full-K per wave, 64 rows/block) -> unscaled bf16 h1; sharded histogram in the tail.
// Stage: 2 batches of 8 float4 loads into registers (static idx) for deep MLP.
__global__ __launch_bounds__(256, 4) void k_gemm1_hist(const float* __restrict__ A, const short* __restrict__ Wb,
                                                       unsigned short* __restrict__ h1, int M,
                                                       const int* __restrict__ ei, int* __restrict__ cnt16,
                                                       int* __restrict__ rank, int E, int N){
  __shared__ unsigned short lds[64*256];   // 32 KB
  int b = blockIdx.x, tid = threadIdx.x;
  int wid = tid >> 6, lane = tid & 63;
  int row0 = b*64 + wid*16;
  int rfrag = lane & 15, grp = lane >> 4;
  char* ldsb = (char*)lds;
  const short8_t* wb = (const short8_t*)Wb + lane;
  f32x4 acc0 = {0.f,0.f,0.f,0.f}, acc1 = acc0, acc2 = acc0, acc3 = acc0;

  int wbase = wid*16*512;
  int wsel  = (lane >> 1);
  int whalf = (lane & 1) << 3;

  // precompute clamped row pointers (uniform rows, per-lane column offset)
  const float* rowp[16];
  #pragma unroll
  for (int r = 0; r < 16; ++r){
    int rowc = row0 + r; if (rowc >= M) rowc = M - 1;
    rowp[r] = A + (size_t)rowc*2048 + lane*4;
  }

  for (int ko = 0; ko < 8; ++ko){
    float4 fv[8];
    // batch 1: rows 0-7
    #pragma unroll
    for (int r = 0; r < 8; ++r) fv[r] = *(const float4*)(rowp[r] + ko*256);
    #pragma unroll
    for (int r = 0; r < 8; ++r){
      uint2 p; p.x = pack2(fv[r].x, fv[r].y); p.y = pack2(fv[r].z, fv[r].w);
      *(uint2*)(ldsb + wbase + r*512 + ((wsel ^ (r & 7)) << 4) + whalf) = p;
    }
    // batch 2: rows 8-15
    #pragma unroll
    for (int r = 0; r < 8; ++r) fv[r] = *(const float4*)(rowp[8 + r] + ko*256);
    #pragma unroll
    for (int r = 0; r < 8; ++r){
      uint2 p; p.x = pack2(fv[r].x, fv[r].y); p.y = pack2(fv[r].z, fv[r].w);
      *(uint2*)(ldsb + wbase + (8 + r)*512 + ((wsel ^ ((8 + r) & 7)) << 4) + whalf) = p;
    }
    asm volatile("s_waitcnt lgkmcnt(0)" ::: "memory");
    #pragma unroll
    for (int kt = 0; kt < 8; ++kt){
      short8_t af = *(const short8_t*)(ldsb + wbase + rfrag*512 + ((((kt<<2) + grp) ^ (rfrag & 7)) << 4));
      int ktg = ko*8 + kt;
      short8_t b0 = wb[(ktg*4+0)*64];
      short8_t b1 = wb[(ktg*4+1)*64];
      short8_t b2 = wb[(ktg*4+2)*64];
      short8_t b3 = wb[(ktg*4+3)*64];
      acc0 = __builtin_amdgcn_mfma_f32_16x16x32_bf16(af, b0, acc0, 0,0,0);
      acc1 = __builtin_amdgcn_mfma_f32_16x16x32_bf16(af, b1, acc1, 0,0,0);
      acc2 = __builtin_amdgcn_mfma_f32_16x16x32_bf16(af, b2, acc2, 0,0,0);
      acc3 = __builtin_amdgcn_mfma_f32_16x16x32_bf16(af, b3, acc3, 0,0,0);
    }
  }

  // C/D: col = lane&15, row = (lane>>4)*4 + reg ; unscaled bf16 out, guarded
  int orow = row0 + grp*4;
  unsigned short* op = h1 + (size_t)orow*64 + rfrag;
  #pragma unroll
  for (int reg = 0; reg < 4; ++reg){
    if (orow + reg < M){
      op[reg*64 +  0] = (unsigned short)f2bf(acc0[reg]);
      op[reg*64 + 16] = (unsigned short)f2bf(acc1[reg]);
      op[reg*64 + 32] = (unsigned short)f2bf(acc2[reg]);
      op[reg*64 + 48] = (unsigned short)f2bf(acc3[reg]);
    }
  }

  // ---- tail: sharded histogram slice (2048 edges/block, shard = b&15) ----
  int lo = b << 11, hi = lo + 2048; if (hi > E) hi = E;
  int* cs = cnt16 + (size_t)(b & 15)*N;
  for (int i = lo + tid; i < hi; i += 256)
    rank[i] = atomicAdd(&cs[ei[E + i]], 1);
}

// ---- parallel scan over sharded counts ----
__global__ __launch_bounds__(256) void k_part(const int* __restrict__ cnt16, int* __restrict__ partial, int N){
  int b = blockIdx.x, t = threadIdx.x;
  int chunk = (N + 255) >> 8;
  int lo = b*chunk, hi = lo + chunk; if (hi > N) hi = N;
  int s = 0;
  for (int i = lo + t; i < hi; i += 256){
    #pragma unroll
    for (int sh = 0; sh < 16; ++sh) s += cnt16[(size_t)sh*N + i];
  }
  __shared__ int sm[256];
  sm[t] = s; __syncthreads();
  for (int d = 128; d; d >>= 1){ if (t < d) sm[t] += sm[t+d]; __syncthreads(); }
  if (t == 0) partial[b] = sm[0];
}

__global__ __launch_bounds__(256) void k_scan2(const int* __restrict__ cnt16, const int* __restrict__ partial,
                                               int* __restrict__ off, int* __restrict__ sbase,
                                               float* __restrict__ dinv, int N){
  int b = blockIdx.x, t = threadIdx.x;
  __shared__ int ps[256];
  ps[t] = partial[t]; __syncthreads();
  for (int d = 1; d < 256; d <<= 1){
    int v = (t >= d) ? ps[t-d] : 0; __syncthreads(); ps[t] += v; __syncthreads();
  }
  int base  = b ? ps[b-1] : 0;
  int total = ps[255];
  int chunk = (N + 255) >> 8;
  int lo = b*chunk, hi = lo + chunk; if (hi > N) hi = N;
  __shared__ int vs[256];
  int run = base;
  for (int j0 = lo; j0 < hi; j0 += 256){
    int i = j0 + t;
    int cs[16]; int c = 0;
    if (i < hi){
      #pragma unroll
      for (int sh = 0; sh < 16; ++sh){ cs[sh] = cnt16[(size_t)sh*N + i]; c += cs[sh]; }
    }
    vs[t] = (i < hi) ? c : 0; __syncthreads();
    for (int d = 1; d < 256; d <<= 1){
      int v = (t >= d) ? vs[t-d] : 0; __syncthreads(); vs[t] += v; __syncthreads();
    }
    if (i < hi){
      int excl = run + vs[t] - c;
      off[i] = excl;
      dinv[i] = rsqrtf((float)(c + 1));
      int runs = excl;
      #pragma unroll
      for (int sh = 0; sh < 16; ++sh){ sbase[(size_t)sh*N + i] = runs; runs += cs[sh]; }
    }
    run += vs[255];
    __syncthreads();
  }
  if (b == 255 && t == 0) off[N] = total;
}

// Atomic-free scatter: shard recomputed from edge index (2048 edges/block in gemm tail).
__global__ __launch_bounds__(256) void k_scatter(const int* __restrict__ ei, const int* __restrict__ sbase,
                                                 const int* __restrict__ rank, int* __restrict__ ebuf,
                                                 int E, int N){
  int i = blockIdx.x*256 + threadIdx.x;
  if (i < E){
    int s = ei[i], d = ei[E + i];
    int sh = (i >> 11) & 15;
    ebuf[sbase[(size_t)sh*N + d] + rank[i]] = s;
  }
}

// GEMM2 (K=64): bf16 A, unscaled bf16 out.
template<int KTILES>
__global__ __launch_bounds__(256) void k_gemm_sm(const unsigned short* __restrict__ Ah,
                                                 const short* __restrict__ Wb,
                                                 unsigned short* __restrict__ out, int M, int lda){
  int wid = threadIdx.x >> 6, lane = threadIdx.x & 63;
  int row0 = (blockIdx.x*4 + wid)*16;
  if (row0 >= M) return;
  int r = lane & 15, g = lane >> 4;
  const short8_t* wb = (const short8_t*)Wb + lane;
  f32x4 acc0 = {0.f,0.f,0.f,0.f}, acc1 = acc0, acc2 = acc0, acc3 = acc0;
  #pragma unroll
  for (int kt = 0; kt < KTILES; ++kt){
    short8_t af = *(const short8_t*)(Ah + (size_t)(row0 + r)*lda + kt*32 + g*8);
    short8_t b0 = wb[(kt*4+0)*64];
    short8_t b1 = wb[(kt*4+1)*64];
    short8_t b2 = wb[(kt*4+2)*64];
    short8_t b3 = wb[(kt*4+3)*64];
    acc0 = __builtin_amdgcn_mfma_f32_16x16x32_bf16(af, b0, acc0, 0,0,0);
    acc1 = __builtin_amdgcn_mfma_f32_16x16x32_bf16(af, b1, acc1, 0,0,0);
    acc2 = __builtin_amdgcn_mfma_f32_16x16x32_bf16(af, b2, acc2, 0,0,0);
    acc3 = __builtin_amdgcn_mfma_f32_16x16x32_bf16(af, b3, acc3, 0,0,0);
  }
  int orow = row0 + g*4;
  unsigned short* op = out + (size_t)orow*64 + r;
  #pragma unroll
  for (int reg = 0; reg < 4; ++reg){
    if (orow + reg < M){
      op[reg*64 +  0] = (unsigned short)f2bf(acc0[reg]);
      op[reg*64 + 16] = (unsigned short)f2bf(acc1[reg]);
      op[reg*64 + 32] = (unsigned short)f2bf(acc2[reg]);
      op[reg*64 + 48] = (unsigned short)f2bf(acc3[reg]);
    }
  }
}

// Gather-aggregate on unscaled h, 8-deep gather pipeline.
template<bool FUSE>
__global__ __launch_bounds__(256) void k_agg(const unsigned short* __restrict__ hin, const int* __restrict__ off,
                                             const int* __restrict__ ebuf, const float* __restrict__ dinv,
                                             const float* __restrict__ bias, void* __restrict__ outp, int N){
  int lane = threadIdx.x & 63, wid = threadIdx.x >> 6;
  float b = bias[lane];
  float fsum = 0.f;
  int stride = gridDim.x*4;
  for (int i = blockIdx.x*4 + wid; i < N; i += stride){
    float di = dinv[i];
    float acc = di*bf2f(hin[(size_t)i*64 + lane]);
    int j  = off[i];
    int j1 = off[i+1];
    for (; j + 8 <= j1; j += 8){
      int s0 = ebuf[j],   s1 = ebuf[j+1], s2 = ebuf[j+2], s3 = ebuf[j+3];
      int s4 = ebuf[j+4], s5 = ebuf[j+5], s6 = ebuf[j+6], s7 = ebuf[j+7];
      float w0 = dinv[s0], w1 = dinv[s1], w2 = dinv[s2], w3 = dinv[s3];
      float w4 = dinv[s4], w5 = dinv[s5], w6 = dinv[s6], w7 = dinv[s7];
      float h0 = bf2f(hin[(size_t)s0*64 + lane]);
      float h1v = bf2f(hin[(size_t)s1*64 + lane]);
      float h2 = bf2f(hin[(size_t)s2*64 + lane]);
      float h3 = bf2f(hin[(size_t)s3*64 + lane]);
      float h4 = bf2f(hin[(size_t)s4*64 + lane]);
      float h5 = bf2f(hin[(size_t)s5*64 + lane]);
      float h6 = bf2f(hin[(size_t)s6*64 + lane]);
      float h7 = bf2f(hin[(size_t)s7*64 + lane]);
      acc += w0*h0 + w1*h1v + w2*h2 + w3*h3 + w4*h4 + w5*h5 + w6*h6 + w7*h7;
    }
    for (; j < j1; ++j){
      int s = ebuf[j];
      acc += dinv[s]*bf2f(hin[(size_t)s*64 + lane]);
    }
    float z = fmaxf(di*acc + b, 0.f);
    if (FUSE) fsum += z;
    else ((unsigned short*)outp)[(size_t)i*64 + lane] = (unsigned short)f2bf(z);
  }
  if (FUSE){
    __shared__ float sm[4][64];
    sm[wid][lane] = fsum;
    __syncthreads();
    if (wid == 0)
      ((float*)outp)[(size_t)blockIdx.x*64 + lane] = sm[0][lane] + sm[1][lane] + sm[2][lane] + sm[3][lane];
  }
}

__global__ __launch_bounds__(256) void k_final(const float* __restrict__ part, float* __restrict__ out,
                                               int NB, float invN){
  int f = blockIdx.x;
  float s = 0.f;
  for (int b = threadIdx.x; b < NB; b += 256) s += part[(size_t)b*64 + f];
  __shared__ float sm[256];
  sm[threadIdx.x] = s; __syncthreads();
  for (int d = 128; d > 0; d >>= 1){
    if (threadIdx.x < d) sm[threadIdx.x] += sm[threadIdx.x + d];
    __syncthreads();
  }
  if (threadIdx.x == 0) out[f] = sm[0]*invN;
}

extern "C" void kernel_launch(void* const* d_in, const int* in_sizes, int n_in,
                              void* d_out, int out_size, void* d_ws, size_t ws_size,
                              hipStream_t stream){
  const float* x  = (const float*)d_in[0];
  const int*   ei = (const int*)d_in[1];
  const float* W1 = (const float*)d_in[2];
  const float* b1 = (const float*)d_in[3];
  const float* W2 = (const float*)d_in[4];
  const float* b2 = (const float*)d_in[5];
  float* out = (float*)d_out;

  const int IN = 2048;
  int N = in_sizes[0] / IN;      // 50000
  int E = in_sizes[1] / 2;       // 1.6M

  char* w = (char*)d_ws;
  auto alloc = [&](size_t bytes){ char* p = w; w += (bytes + 255) & ~255ULL; return (void*)p; };
  int*   cnt16   = (int*)  alloc((size_t)16*N*4);
  int*   off     = (int*)  alloc((size_t)(N+1)*4);
  int*   sbase   = (int*)  alloc((size_t)16*N*4);
  float* dinv    = (float*)alloc((size_t)N*4);
  int*   partial = (int*)  alloc(256*4);
  int*   rank    = (int*)  alloc((size_t)E*4);
  int*   ebuf    = (int*)  alloc((size_t)E*4);
  short* Wb1     = (short*)alloc((size_t)64*2048*2);
  short* Wb2     = (short*)alloc((size_t)2*2048*2);
  unsigned short* h1 = (unsigned short*)alloc((size_t)N*64*2);
  unsigned short* z1 = (unsigned short*)alloc((size_t)N*64*2);
  const int NB2 = 2048;
  float* part    = (float*)alloc((size_t)NB2*64*4);

  int EB = (E + 255)/256;            // 6250
  int GB = (N + 63)/64;              // 782 ; 782*2048 >= E (hist slices cover all edges)
  int smblocks = ((N + 15)/16 + 3)/4;

  hipMemsetAsync(cnt16, 0, (size_t)16*N*4, stream);
  k_wconv2 <<<(64*2048 + 2*2048 + 255)/256, 256, 0, stream>>>(W1, Wb1, W2, Wb2);
  k_gemm1_hist<<<GB, 256, 0, stream>>>(x, Wb1, h1, N, ei, cnt16, rank, E, N);
  k_part   <<<256, 256, 0, stream>>>(cnt16, partial, N);
  k_scan2  <<<256, 256, 0, stream>>>(cnt16, partial, off, sbase, dinv, N);
  k_scatter<<<EB, 256, 0, stream>>>(ei, sbase, rank, ebuf, E, N);
  k_agg<false><<<NB2, 256, 0, stream>>>(h1, off, ebuf, dinv, b1, (void*)z1, N);
  k_gemm_sm<2><<<smblocks, 256, 0, stream>>>(z1, Wb2, h1, N, 64);
  k_agg<true> <<<NB2, 256, 0, stream>>>(h1, off, ebuf, dinv, b2, (void*)part, N);
  k_final  <<<64, 256, 0, stream>>>(part, out, NB2, 1.0f/(float)N);
}

// Round 12
// 319.581 us; speedup vs baseline: 1.2902x; 1.0878x over previous
//
#include <hip/hip_runtime.h>
#include <hip/hip_bf16.h>

typedef __attribute__((ext_vector_type(8))) short short8_t;
typedef __attribute__((ext_vector_type(4))) float f32x4;

__device__ __forceinline__ short f2bf(float x){
  union { float f; unsigned u; } v; v.f = x;
  unsigned r = v.u + 0x7fffu + ((v.u >> 16) & 1u);
  return (short)(r >> 16);
}
__device__ __forceinline__ float bf2f(unsigned short u){
  union { unsigned u; float f; } v; v.u = ((unsigned)u) << 16; return v.f;
}
// non-volatile: pure value op, compiler schedules freely (R8 lesson: volatile in load path = convoy)
__device__ __forceinline__ unsigned cvtpk(float lo, float hi){
  unsigned r; asm("v_cvt_pk_bf16_f32 %0, %1, %2" : "=v"(r) : "v"(lo), "v"(hi)); return r;
}
// async global->LDS, 16B/lane, LDS dest = uniform base + lane*16 (linear)
__device__ __forceinline__ void gll16(const float* g, void* l){
  __builtin_amdgcn_global_load_lds((const __attribute__((address_space(1))) char*)g,
                                   (__attribute__((address_space(3))) char*)l, 16, 0, 0);
}

// Both W -> bf16 fragment layouts in one launch.
__global__ __launch_bounds__(256) void k_wconv2(const float* __restrict__ W1, short* __restrict__ Wb1,
                                                const float* __restrict__ W2, short* __restrict__ Wb2){
  int tid = blockIdx.x*256 + threadIdx.x;
  const float* W; short* Wb; int t;
  if (tid < 64*2048){ W = W1; Wb = Wb1; t = tid; }
  else if (tid < 64*2048 + 2*2048){ W = W2; Wb = Wb2; t = tid - 64*2048; }
  else return;
  int e  = t & 7;
  int l  = (t >> 3) & 63;
  int nt = (t >> 9) & 3;
  int kt = t >> 11;
  int k  = kt*32 + (l >> 4)*8 + e;
  int col = nt*16 + (l & 15);
  Wb[t] = f2bf(W[(size_t)k*64 + col]);
}

// GEMM1: global_load_lds staging (zero staging VGPRs), fp32 in LDS (pitch 1040B: 2-way banks = free),
// cvt_pk on consume. 4 waves x 16 rows, full K. Unscaled bf16 out + sharded histogram tail.
__global__ __launch_bounds__(256) void k_gemm1_hist(const float* __restrict__ A, const short* __restrict__ Wb,
                                                    unsigned short* __restrict__ h1, int M,
                                                    const int* __restrict__ ei, int* __restrict__ cnt16,
                                                    int* __restrict__ rank, int E, int N){
  __shared__ char lds[4*16*1040];   // 66560 B -> 2 blocks/CU
  int b = blockIdx.x, tid = threadIdx.x;
  int wid = tid >> 6, lane = tid & 63;
  int row0 = b*64 + wid*16;
  int rfrag = lane & 15, grp = lane >> 4;
  char* wls = lds + wid*16*1040;    // wave-private region: no barriers needed
  const short8_t* wb = (const short8_t*)Wb + lane;
  f32x4 acc0 = {0.f,0.f,0.f,0.f}, acc1 = acc0, acc2 = acc0, acc3 = acc0;

  // uniform clamped rows
  int rowc[16];
  #pragma unroll
  for (int r = 0; r < 16; ++r){
    int rc = row0 + r; rowc[r] = (rc < M) ? rc : (M - 1);
  }

  for (int ko = 0; ko < 8; ++ko){
    // ---- stage: 16 x (1KB contiguous row slice) via fire-and-forget gll ----
    #pragma unroll
    for (int r = 0; r < 16; ++r)
      gll16(A + (size_t)rowc[r]*2048 + ko*256 + lane*4, wls + r*1040);
    asm volatile("s_waitcnt vmcnt(0)" ::: "memory");
    __builtin_amdgcn_sched_barrier(0);
    // ---- consume: 8 k-subtiles of 32 ----
    #pragma unroll
    for (int kt = 0; kt < 8; ++kt){
      const float* fp = (const float*)(wls + rfrag*1040 + (kt*32 + grp*8)*4);
      float4 a0 = *(const float4*)fp;
      float4 a1 = *(const float4*)(fp + 4);
      union { unsigned u[4]; short8_t s; } af;
      af.u[0] = cvtpk(a0.x, a0.y);
      af.u[1] = cvtpk(a0.z, a0.w);
      af.u[2] = cvtpk(a1.x, a1.y);
      af.u[3] = cvtpk(a1.z, a1.w);
      int ktg = ko*8 + kt;
      short8_t b0 = wb[(ktg*4+0)*64];
      short8_t b1 = wb[(ktg*4+1)*64];
      short8_t b2 = wb[(ktg*4+2)*64];
      short8_t b3 = wb[(ktg*4+3)*64];
      acc0 = __builtin_amdgcn_mfma_f32_16x16x32_bf16(af.s, b0, acc0, 0,0,0);
      acc1 = __builtin_amdgcn_mfma_f32_16x16x32_bf16(af.s, b1, acc1, 0,0,0);
      acc2 = __builtin_amdgcn_mfma_f32_16x16x32_bf16(af.s, b2, acc2, 0,0,0);
      acc3 = __builtin_amdgcn_mfma_f32_16x16x32_bf16(af.s, b3, acc3, 0,0,0);
    }
  }

  // C/D: col = lane&15, row = (lane>>4)*4 + reg ; unscaled bf16 out, guarded
  int orow = row0 + grp*4;
  unsigned short* op = h1 + (size_t)orow*64 + rfrag;
  #pragma unroll
  for (int reg = 0; reg < 4; ++reg){
    if (orow + reg < M){
      op[reg*64 +  0] = (unsigned short)f2bf(acc0[reg]);
      op[reg*64 + 16] = (unsigned short)f2bf(acc1[reg]);
      op[reg*64 + 32] = (unsigned short)f2bf(acc2[reg]);
      op[reg*64 + 48] = (unsigned short)f2bf(acc3[reg]);
    }
  }

  // ---- tail: sharded histogram slice (2048 edges/block, shard = b&15 -> XCD-affine) ----
  int lo = b << 11, hi = lo + 2048; if (hi > E) hi = E;
  int* cs = cnt16 + (size_t)(b & 15)*N;
  for (int i = lo + tid; i < hi; i += 256)
    rank[i] = atomicAdd(&cs[ei[E + i]], 1);
}

// ---- parallel scan over sharded counts ----
__global__ __launch_bounds__(256) void k_part(const int* __restrict__ cnt16, int* __restrict__ partial, int N){
  int b = blockIdx.x, t = threadIdx.x;
  int chunk = (N + 255) >> 8;
  int lo = b*chunk, hi = lo + chunk; if (hi > N) hi = N;
  int s = 0;
  for (int i = lo + t; i < hi; i += 256){
    #pragma unroll
    for (int sh = 0; sh < 16; ++sh) s += cnt16[(size_t)sh*N + i];
  }
  __shared__ int sm[256];
  sm[t] = s; __syncthreads();
  for (int d = 128; d; d >>= 1){ if (t < d) sm[t] += sm[t+d]; __syncthreads(); }
  if (t == 0) partial[b] = sm[0];
}

__global__ __launch_bounds__(256) void k_scan2(const int* __restrict__ cnt16, const int* __restrict__ partial,
                                               int* __restrict__ off, int* __restrict__ sbase,
                                               float* __restrict__ dinv, int N){
  int b = blockIdx.x, t = threadIdx.x;
  __shared__ int ps[256];
  ps[t] = partial[t]; __syncthreads();
  for (int d = 1; d < 256; d <<= 1){
    int v = (t >= d) ? ps[t-d] : 0; __syncthreads(); ps[t] += v; __syncthreads();
  }
  int base  = b ? ps[b-1] : 0;
  int total = ps[255];
  int chunk = (N + 255) >> 8;
  int lo = b*chunk, hi = lo + chunk; if (hi > N) hi = N;
  __shared__ int vs[256];
  int run = base;
  for (int j0 = lo; j0 < hi; j0 += 256){
    int i = j0 + t;
    int cs[16]; int c = 0;
    if (i < hi){
      #pragma unroll
      for (int sh = 0; sh < 16; ++sh){ cs[sh] = cnt16[(size_t)sh*N + i]; c += cs[sh]; }
    }
    vs[t] = (i < hi) ? c : 0; __syncthreads();
    for (int d = 1; d < 256; d <<= 1){
      int v = (t >= d) ? vs[t-d] : 0; __syncthreads(); vs[t] += v; __syncthreads();
    }
    if (i < hi){
      int excl = run + vs[t] - c;
      off[i] = excl;
      dinv[i] = rsqrtf((float)(c + 1));
      int runs = excl;
      #pragma unroll
      for (int sh = 0; sh < 16; ++sh){ sbase[(size_t)sh*N + i] = runs; runs += cs[sh]; }
    }
    run += vs[255];
    __syncthreads();
  }
  if (b == 255 && t == 0) off[N] = total;
}

// Atomic-free scatter: shard recomputed from edge index (2048 edges/block in gemm tail).
__global__ __launch_bounds__(256) void k_scatter(const int* __restrict__ ei, const int* __restrict__ sbase,
                                                 const int* __restrict__ rank, int* __restrict__ ebuf,
                                                 int E, int N){
  int i = blockIdx.x*256 + threadIdx.x;
  if (i < E){
    int s = ei[i], d = ei[E + i];
    int sh = (i >> 11) & 15;
    ebuf[sbase[(size_t)sh*N + d] + rank[i]] = s;
  }
}

// GEMM2 (K=64): bf16 A, unscaled bf16 out.
template<int KTILES>
__global__ __launch_bounds__(256) void k_gemm_sm(const unsigned short* __restrict__ Ah,
                                                 const short* __restrict__ Wb,
                                                 unsigned short* __restrict__ out, int M, int lda){
  int wid = threadIdx.x >> 6, lane = threadIdx.x & 63;
  int row0 = (blockIdx.x*4 + wid)*16;
  if (row0 >= M) return;
  int r = lane & 15, g = lane >> 4;
  const short8_t* wb = (const short8_t*)Wb + lane;
  f32x4 acc0 = {0.f,0.f,0.f,0.f}, acc1 = acc0, acc2 = acc0, acc3 = acc0;
  #pragma unroll
  for (int kt = 0; kt < KTILES; ++kt){
    short8_t af = *(const short8_t*)(Ah + (size_t)(row0 + r)*lda + kt*32 + g*8);
    short8_t b0 = wb[(kt*4+0)*64];
    short8_t b1 = wb[(kt*4+1)*64];
    short8_t b2 = wb[(kt*4+2)*64];
    short8_t b3 = wb[(kt*4+3)*64];
    acc0 = __builtin_amdgcn_mfma_f32_16x16x32_bf16(af, b0, acc0, 0,0,0);
    acc1 = __builtin_amdgcn_mfma_f32_16x16x32_bf16(af, b1, acc1, 0,0,0);
    acc2 = __builtin_amdgcn_mfma_f32_16x16x32_bf16(af, b2, acc2, 0,0,0);
    acc3 = __builtin_amdgcn_mfma_f32_16x16x32_bf16(af, b3, acc3, 0,0,0);
  }
  int orow = row0 + g*4;
  unsigned short* op = out + (size_t)orow*64 + r;
  #pragma unroll
  for (int reg = 0; reg < 4; ++reg){
    if (orow + reg < M){
      op[reg*64 +  0] = (unsigned short)f2bf(acc0[reg]);
      op[reg*64 + 16] = (unsigned short)f2bf(acc1[reg]);
      op[reg*64 + 32] = (unsigned short)f2bf(acc2[reg]);
      op[reg*64 + 48] = (unsigned short)f2bf(acc3[reg]);
    }
  }
}

// Gather-aggregate on unscaled h, 8-deep gather pipeline.
template<bool FUSE>
__global__ __launch_bounds__(256) void k_agg(const unsigned short* __restrict__ hin, const int* __restrict__ off,
                                             const int* __restrict__ ebuf, const float* __restrict__ dinv,
                                             const float* __restrict__ bias, void* __restrict__ outp, int N){
  int lane = threadIdx.x & 63, wid = threadIdx.x >> 6;
  float b = bias[lane];
  float fsum = 0.f;
  int stride = gridDim.x*4;
  for (int i = blockIdx.x*4 + wid; i < N; i += stride){
    float di = dinv[i];
    float acc = di*bf2f(hin[(size_t)i*64 + lane]);
    int j  = off[i];
    int j1 = off[i+1];
    for (; j + 8 <= j1; j += 8){
      int s0 = ebuf[j],   s1 = ebuf[j+1], s2 = ebuf[j+2], s3 = ebuf[j+3];
      int s4 = ebuf[j+4], s5 = ebuf[j+5], s6 = ebuf[j+6], s7 = ebuf[j+7];
      float w0 = dinv[s0], w1 = dinv[s1], w2 = dinv[s2], w3 = dinv[s3];
      float w4 = dinv[s4], w5 = dinv[s5], w6 = dinv[s6], w7 = dinv[s7];
      float h0 = bf2f(hin[(size_t)s0*64 + lane]);
      float h1v = bf2f(hin[(size_t)s1*64 + lane]);
      float h2 = bf2f(hin[(size_t)s2*64 + lane]);
      float h3 = bf2f(hin[(size_t)s3*64 + lane]);
      float h4 = bf2f(hin[(size_t)s4*64 + lane]);
      float h5 = bf2f(hin[(size_t)s5*64 + lane]);
      float h6 = bf2f(hin[(size_t)s6*64 + lane]);
      float h7 = bf2f(hin[(size_t)s7*64 + lane]);
      acc += w0*h0 + w1*h1v + w2*h2 + w3*h3 + w4*h4 + w5*h5 + w6*h6 + w7*h7;
    }
    for (; j < j1; ++j){
      int s = ebuf[j];
      acc += dinv[s]*bf2f(hin[(size_t)s*64 + lane]);
    }
    float z = fmaxf(di*acc + b, 0.f);
    if (FUSE) fsum += z;
    else ((unsigned short*)outp)[(size_t)i*64 + lane] = (unsigned short)f2bf(z);
  }
  if (FUSE){
    __shared__ float sm[4][64];
    sm[wid][lane] = fsum;
    __syncthreads();
    if (wid == 0)
      ((float*)outp)[(size_t)blockIdx.x*64 + lane] = sm[0][lane] + sm[1][lane] + sm[2][lane] + sm[3][lane];
  }
}

__global__ __launch_bounds__(256) void k_final(const float* __restrict__ part, float* __restrict__ out,
                                               int NB, float invN){
  int f = blockIdx.x;
  float s = 0.f;
  for (int b = threadIdx.x; b < NB; b += 256) s += part[(size_t)b*64 + f];
  __shared__ float sm[256];
  sm[threadIdx.x] = s; __syncthreads();
  for (int d = 128; d > 0; d >>= 1){
    if (threadIdx.x < d) sm[threadIdx.x] += sm[threadIdx.x + d];
    __syncthreads();
  }
  if (threadIdx.x == 0) out[f] = sm[0]*invN;
}

extern "C" void kernel_launch(void* const* d_in, const int* in_sizes, int n_in,
                              void* d_out, int out_size, void* d_ws, size_t ws_size,
                              hipStream_t stream){
  const float* x  = (const float*)d_in[0];
  const int*   ei = (const int*)d_in[1];
  const float* W1 = (const float*)d_in[2];
  const float* b1 = (const float*)d_in[3];
  const float* W2 = (const float*)d_in[4];
  const float* b2 = (const float*)d_in[5];
  float* out = (float*)d_out;

  const int IN = 2048;
  int N = in_sizes[0] / IN;      // 50000
  int E = in_sizes[1] / 2;       // 1.6M

  char* w = (char*)d_ws;
  auto alloc = [&](size_t bytes){ char* p = w; w += (bytes + 255) & ~255ULL; return (void*)p; };
  int*   cnt16   = (int*)  alloc((size_t)16*N*4);
  int*   off     = (int*)  alloc((size_t)(N+1)*4);
  int*   sbase   = (int*)  alloc((size_t)16*N*4);
  float* dinv    = (float*)alloc((size_t)N*4);
  int*   partial = (int*)  alloc(256*4);
  int*   rank    = (int*)  alloc((size_t)E*4);
  int*   ebuf    = (int*)  alloc((size_t)E*4);
  short* Wb1     = (short*)alloc((size_t)64*2048*2);
  short* Wb2     = (short*)alloc((size_t)2*2048*2);
  unsigned short* h1 = (unsigned short*)alloc((size_t)N*64*2);
  unsigned short* z1 = (unsigned short*)alloc((size_t)N*64*2);
  const int NB2 = 2048;
  float* part    = (float*)alloc((size_t)NB2*64*4);

  int EB = (E + 255)/256;            // 6250
  int GB = (N + 63)/64;              // 782 ; 782*2048 >= E (hist slices cover all edges)
  int smblocks = ((N + 15)/16 + 3)/4;

  hipMemsetAsync(cnt16, 0, (size_t)16*N*4, stream);
  k_wconv2 <<<(64*2048 + 2*2048 + 255)/256, 256, 0, stream>>>(W1, Wb1, W2, Wb2);
  k_gemm1_hist<<<GB, 256, 0, stream>>>(x, Wb1, h1, N, ei, cnt16, rank, E, N);
  k_part   <<<256, 256, 0, stream>>>(cnt16, partial, N);
  k_scan2  <<<256, 256, 0, stream>>>(cnt16, partial, off, sbase, dinv, N);
  k_scatter<<<EB, 256, 0, stream>>>(ei, sbase, rank, ebuf, E, N);
  k_agg<false><<<NB2, 256, 0, stream>>>(h1, off, ebuf, dinv, b1, (void*)z1, N);
  k_gemm_sm<2><<<smblocks, 256, 0, stream>>>(z1, Wb2, h1, N, 64);
  k_agg<true> <<<NB2, 256, 0, stream>>>(h1, off, ebuf, dinv, b2, (void*)part, N);
  k_final  <<<64, 256, 0, stream>>>(part, out, NB2, 1.0f/(float)N);
}